// Round 7
// baseline (672.006 us; speedup 1.0000x reference)
//
#include <hip/hip_runtime.h>
#include <math.h>

#define T_STEPS 19
#define V 50257
#define EMB 300
#define HDIM 512
#define NP 256
#define ML 50
#define CIN 812
#define NEGV -1e9f
#define NBLK 64    // blocks in the persistent recurrence kernel (1 flag per lane)

// ---- workspace layout (float indices) ----
#define OFF_X      0                         // 19*300 = 5700
#define OFF_POP    5700                      // 19*256
#define OFF_PL     10564                     // 19*256
#define OFF_PC     15428                     // 19*512
#define OFF_HS     25156                     // 20*512 (Hs[0]=input hidden)
#define OFF_H1OP   35396                     // 256
#define OFF_H1L    35652                     // 256
#define OFF_C1     37444                     // 512
#define OFF_G      37956                     // 512
#define OFF_MPROP  38788                     // 512*256 = 131072
#define OFF_MENC   169860                    // 512*50  = 25600
#define OFF_W2OPT  195460                    // 256*256 = 65536 (float4-col layout)
#define OFF_W2LT   260996                    // 64*256  = 16384 (float4-col layout)
#define OFF_BAR    277380                    // flags @ +16 + 16*b (64B stride)

// ---- output layout (floats) ----
#define OUT_LOGITS 0
#define OUT_ATTW   ((long)T_STEPS * V)
#define OUT_ATTOB  (OUT_ATTW + (long)T_STEPS * ML)

__device__ __forceinline__ float wred(float v) {
  v += __shfl_xor(v, 32, 64);
  v += __shfl_xor(v, 16, 64);
  v += __shfl_xor(v, 8, 64);
  v += __shfl_xor(v, 4, 64);
  v += __shfl_xor(v, 2, 64);
  v += __shfl_xor(v, 1, 64);
  return v;
}

__device__ __forceinline__ float dot4(float4 a, float4 b) {
  return a.x * b.x + a.y * b.y + a.z * b.z + a.w * b.w;
}

// ---- agent-coherent access helpers (bypass non-coherent L1/L2; hit the MALL) ----
__device__ __forceinline__ void gstore(float* p, float v) {
  __hip_atomic_store(p, v, __ATOMIC_RELAXED, __HIP_MEMORY_SCOPE_AGENT);
}
__device__ __forceinline__ float ld1c(const float* p) {
  return __hip_atomic_load(p, __ATOMIC_RELAXED, __HIP_MEMORY_SCOPE_AGENT);
}
__device__ __forceinline__ float2 ld2c(const float* p) {
  unsigned long long u = __hip_atomic_load((const unsigned long long*)p,
                                           __ATOMIC_RELAXED, __HIP_MEMORY_SCOPE_AGENT);
  float2 r;
  r.x = __uint_as_float((unsigned)u);
  r.y = __uint_as_float((unsigned)(u >> 32));
  return r;
}
__device__ __forceinline__ float4 ld4c(const float* p) {
  float2 a = ld2c(p), b = ld2c(p + 2);
  return make_float4(a.x, a.y, b.x, b.y);
}

// Split grid barrier (fence-free, all-poll-all). arrive: drain + flag store.
// wait: poll all 64 flags (one per lane of wave 0). Independent work goes between.
__device__ __forceinline__ void gbar_arrive(float* wsb, unsigned bar) {
  asm volatile("s_waitcnt vmcnt(0)" ::: "memory");
  __syncthreads();
  if (threadIdx.x == 0) {
    unsigned* flags = (unsigned*)(wsb + OFF_BAR) + 16;
    __hip_atomic_store(flags + 16 * blockIdx.x, bar, __ATOMIC_RELAXED, __HIP_MEMORY_SCOPE_AGENT);
  }
}
__device__ __forceinline__ void gbar_wait(float* wsb, unsigned bar) {
  if (threadIdx.x < 64) {
    unsigned* f = (unsigned*)(wsb + OFF_BAR) + 16 + 16 * threadIdx.x;
    while (__hip_atomic_load(f, __ATOMIC_RELAXED, __HIP_MEMORY_SCOPE_AGENT) < bar) {
      __builtin_amdgcn_s_sleep(1);
    }
  }
  __syncthreads();
}

// Precompute X = relu(emb[token]) for all steps; copy Hs[0].
__global__ void k_pre1(const int* __restrict__ tok0, const int* __restrict__ ans,
                       const float* __restrict__ emb, const float* __restrict__ hidden,
                       float* __restrict__ ws) {
  int tid = blockIdx.x * 256 + threadIdx.x;
  if (tid < T_STEPS * EMB) {
    int s = tid / EMB, j = tid - s * EMB;
    int t = (s == 0) ? tok0[0] : ans[s];
    float v = emb[(long)t * EMB + j];
    ws[OFF_X + tid] = v > 0.f ? v : 0.f;
  } else {
    int k = tid - T_STEPS * EMB;
    if (k < HDIM) ws[OFF_HS + k] = hidden[k];
  }
}

// P_op/P_l/P_c: x-column partials + layer-1 biases. wave-per-row, 19*1024 rows.
__global__ void k_pre2(const float* __restrict__ w1op, const float* __restrict__ b1op,
                       const float* __restrict__ w1l,  const float* __restrict__ b1l,
                       const float* __restrict__ wc1,  const float* __restrict__ bc1,
                       float* __restrict__ ws) {
  int gw = (blockIdx.x * 256 + threadIdx.x) >> 6;
  int lane = threadIdx.x & 63;
  int s = gw >> 10;
  int rr = gw & 1023;
  if (s >= T_STEPS) return;
  const float* wrow; const float* bias; float* dst; int r;
  if (rr < 256)      { r = rr;       wrow = w1op + (long)r * CIN; bias = b1op; dst = ws + OFF_POP + s * 256 + r; }
  else if (rr < 512) { r = rr - 256; wrow = w1l  + (long)r * CIN; bias = b1l;  dst = ws + OFF_PL  + s * 256 + r; }
  else               { r = rr - 512; wrow = wc1  + (long)r * CIN; bias = bc1;  dst = ws + OFF_PC  + s * 512 + r; }
  const float* x = ws + OFF_X + s * EMB;
  float acc = 0.f;
#pragma unroll
  for (int it = 0; it < 5; ++it) {
    int j = it * 64 + lane;
    if (j < EMB) acc += wrow[j] * x[j];
  }
  acc = wred(acc);
  if (lane == 0) *dst = acc + bias[r];
}

// M_prop[r][p] = sum_k cmb_w1[r][556+k]*prop[p][k]; M_enc[r][j] = sum_k cmb_w1[r][300+k]*enc[j][k]
#define LDSF 12850
__global__ void __launch_bounds__(256) k_mprep(const float* __restrict__ cw1,
                                               const float* __restrict__ prop,
                                               const float* __restrict__ enc,
                                               float* __restrict__ ws) {
  __shared__ float lds[LDSF];
  int tid = threadIdx.x, r = blockIdx.x;
  float acc = 0.f;
  for (int kc = 0; kc < 8; ++kc) {
    __syncthreads();
    // stage prop[:, kc*32 .. +32] -> lds [256][33]
#pragma unroll
    for (int i = 0; i < 8; ++i) {
      int f = tid + 256 * i; int row = f >> 3, q = f & 7;
      float4 v = *(const float4*)(prop + (long)row * 256 + kc * 32 + 4 * q);
      float* p = lds + row * 33 + 4 * q;
      p[0] = v.x; p[1] = v.y; p[2] = v.z; p[3] = v.w;
    }
    __syncthreads();
    const float* wbase = cw1 + (long)r * CIN + 556 + kc * 32;
    const float* pl = lds + tid * 33;
#pragma unroll
    for (int k4 = 0; k4 < 8; ++k4) {
      float4 w4 = *(const float4*)(wbase + 4 * k4);
      const float* pp = pl + 4 * k4;
      acc += w4.x * pp[0] + w4.y * pp[1] + w4.z * pp[2] + w4.w * pp[3];
    }
  }
  ws[OFF_MPROP + (long)r * 256 + tid] = acc;
  // enc part: stage all of enc [50][256] -> lds [50][257]
  __syncthreads();
  for (int i = 0; i < 13; ++i) {
    int f = tid + 256 * i;
    if (f < 3200) {
      int row = f >> 6, q = f & 63;
      float4 v = *(const float4*)(enc + (long)row * 256 + 4 * q);
      float* p = lds + row * 257 + 4 * q;
      p[0] = v.x; p[1] = v.y; p[2] = v.z; p[3] = v.w;
    }
  }
  __syncthreads();
  if (tid < ML) {
    const float* wb2 = cw1 + (long)r * CIN + 300;
    const float* el = lds + tid * 257;
    float a2 = 0.f;
#pragma unroll 8
    for (int k = 0; k < 256; ++k) a2 += wb2[k] * el[k];
    ws[OFF_MENC + (long)r * ML + tid] = a2;
  }
}

// Transpose w2op/w2l into float4-per-column layout:
// w2opT4[(k>>2)*1024 + r*4 + (k&3)] = w2op[r][k];  w2lT4[(k>>2)*256 + r*4 + (k&3)] = w2l[r][k]
__global__ void k_pre4(const float* __restrict__ w2op, const float* __restrict__ w2l,
                       float* __restrict__ ws) {
  int r = blockIdx.x;      // 0..255
  int k = threadIdx.x;     // 0..255
  ws[OFF_W2OPT + (k >> 2) * 1024 + r * 4 + (k & 3)] = w2op[(long)r * 256 + k];
  if (r < ML) ws[OFF_W2LT + (k >> 2) * 256 + r * 4 + (k & 3)] = w2l[(long)r * 256 + k];
}

// Persistent fused recurrence: 19 steps x 4 phases (A, BC, D, E), split barriers.
// 64 blocks x 256 threads = 256 waves; wave wv owns rows {2wv, 2wv+1}.
__global__ void __launch_bounds__(256) k_recur(
    const float* __restrict__ w1op, const float* __restrict__ w1l,
    const float* __restrict__ whh,  const float* __restrict__ bhh,
    const float* __restrict__ b2op, const float* __restrict__ b2l,
    const int* __restrict__ obj_mask, const int* __restrict__ lang_mask,
    const float* __restrict__ wc2,  const float* __restrict__ bc2,
    const float* __restrict__ wih,  const float* __restrict__ bih,
    float* ws, float* __restrict__ out) {
  const int tid = threadIdx.x;
  const int lane = tid & 63;
  const int wv = (blockIdx.x << 2) + (tid >> 6);   // 0..255
  const int r0 = 2 * wv, r1 = 2 * wv + 1;          // owned rows 0..511
  unsigned bar = 1;
  __shared__ float red[256];
  __shared__ __align__(16) float sm_aop[256];
  __shared__ float sm_al[64];
  __shared__ __align__(16) float sm_h1op[256];
  __shared__ __align__(16) float sm_h1l[256];

  for (int s = 0; s < T_STEPS; ++s) {
    float ghr0, ghz0, ghn0, ghr1, ghz1, ghn1;  // GRU h-side partials (A -> E, same wave)
    // ---------- Phase A: h1 rows {r0,r1}; arrive; gh (hidden behind barrier); wait ----------
    {
      const float* h = ws + OFF_HS + s * HDIM;
      float4 ha = ld4c(h + 4 * lane);
      float4 hb = ld4c(h + 256 + 4 * lane);
      const float* wa0 = (r0 < 256) ? (w1op + (long)r0 * CIN + 300) : (w1l + (long)(r0 - 256) * CIN + 300);
      const float* wa1 = (r1 < 256) ? (w1op + (long)r1 * CIN + 300) : (w1l + (long)(r1 - 256) * CIN + 300);
      float a0 = dot4(*(const float4*)(wa0 + 4 * lane), ha) + dot4(*(const float4*)(wa0 + 256 + 4 * lane), hb);
      float a1 = dot4(*(const float4*)(wa1 + 4 * lane), ha) + dot4(*(const float4*)(wa1 + 256 + 4 * lane), hb);
      a0 = wred(a0); a1 = wred(a1);
      if (lane == 0) {
        float v0 = a0 + ((r0 < 256) ? ws[OFF_POP + s * 256 + r0] : ws[OFF_PL + s * 256 + (r0 - 256)]);
        float v1 = a1 + ((r1 < 256) ? ws[OFF_POP + s * 256 + r1] : ws[OFF_PL + s * 256 + (r1 - 256)]);
        float* d0 = (r0 < 256) ? (ws + OFF_H1OP + r0) : (ws + OFF_H1L + (r0 - 256));
        float* d1 = (r1 < 256) ? (ws + OFF_H1OP + r1) : (ws + OFF_H1L + (r1 - 256));
        gstore(d0, v0 > 0.f ? v0 : 0.f);
        gstore(d1, v1 > 0.f ? v1 : 0.f);
      }
      gbar_arrive(ws, bar);
      // ---- gap work: gh rows (consumed in E by this same wave) ----
      const float* p0 = whh + (long)r0 * HDIM;
      const float* p1 = whh + (long)(r0 + 512) * HDIM;
      const float* p2 = whh + (long)(r0 + 1024) * HDIM;
      const float* p3 = whh + (long)r1 * HDIM;
      const float* p4 = whh + (long)(r1 + 512) * HDIM;
      const float* p5 = whh + (long)(r1 + 1024) * HDIM;
      float b0 = dot4(*(const float4*)(p0 + 4 * lane), ha) + dot4(*(const float4*)(p0 + 256 + 4 * lane), hb);
      float b1 = dot4(*(const float4*)(p1 + 4 * lane), ha) + dot4(*(const float4*)(p1 + 256 + 4 * lane), hb);
      float b2 = dot4(*(const float4*)(p2 + 4 * lane), ha) + dot4(*(const float4*)(p2 + 256 + 4 * lane), hb);
      float b3 = dot4(*(const float4*)(p3 + 4 * lane), ha) + dot4(*(const float4*)(p3 + 256 + 4 * lane), hb);
      float b4 = dot4(*(const float4*)(p4 + 4 * lane), ha) + dot4(*(const float4*)(p4 + 256 + 4 * lane), hb);
      float b5 = dot4(*(const float4*)(p5 + 4 * lane), ha) + dot4(*(const float4*)(p5 + 256 + 4 * lane), hb);
      b0 = wred(b0); b1 = wred(b1); b2 = wred(b2);
      b3 = wred(b3); b4 = wred(b4); b5 = wred(b5);
      ghr0 = b0 + bhh[r0]; ghz0 = b1 + bhh[512 + r0]; ghn0 = b2 + bhh[1024 + r0];
      ghr1 = b3 + bhh[r1]; ghz1 = b4 + bhh[512 + r1]; ghn1 = b5 + bhh[1024 + r1];
      gbar_wait(ws, bar); bar++;
    }
    // ---------- Phase BC: in-block logits (thread-owns-row) + softmax + c1 rows ----------
    float4 wc0a, wc0b, wc1a, wc1b;   // wc2 prefetch (BC gap -> D)
    {
      sm_h1op[tid] = ld1c(ws + OFF_H1OP + tid);
      sm_h1l[tid]  = ld1c(ws + OFF_H1L + tid);
      __syncthreads();
      float lo = b2op[tid];
      const float* w2T = ws + OFF_W2OPT;
#pragma unroll 8
      for (int k4 = 0; k4 < 64; ++k4) {
        float4 h4 = *(const float4*)(&sm_h1op[4 * k4]);
        float4 w4 = *(const float4*)(&w2T[k4 * 1024 + tid * 4]);
        lo += dot4(w4, h4);
      }
      float llg = 0.f;
      if (tid < ML) {
        llg = b2l[tid];
        const float* wlT = ws + OFF_W2LT;
#pragma unroll 8
        for (int k4 = 0; k4 < 64; ++k4) {
          float4 h4 = *(const float4*)(&sm_h1l[4 * k4]);
          float4 w4 = *(const float4*)(&wlT[k4 * 256 + tid * 4]);
          llg += dot4(w4, h4);
        }
      }
      // softmax (object)
      float vo = (obj_mask[tid] != 0) ? NEGV : lo;
      red[tid] = vo; __syncthreads();
      for (int st = 128; st > 0; st >>= 1) { if (tid < st) red[tid] = fmaxf(red[tid], red[tid + st]); __syncthreads(); }
      float mo = red[0]; __syncthreads();
      float eo = expf(vo - mo);
      red[tid] = eo; __syncthreads();
      for (int st = 128; st > 0; st >>= 1) { if (tid < st) red[tid] += red[tid + st]; __syncthreads(); }
      float aop = eo / red[0];
      sm_aop[tid] = aop;
      __syncthreads();
      // softmax (language)
      float vl = (tid < ML) ? ((lang_mask[tid] != 0) ? NEGV : llg) : -3e38f;
      red[tid] = vl; __syncthreads();
      for (int st = 128; st > 0; st >>= 1) { if (tid < st) red[tid] = fmaxf(red[tid], red[tid + st]); __syncthreads(); }
      float ml_ = red[0]; __syncthreads();
      float el = (tid < ML) ? expf(vl - ml_) : 0.f;
      red[tid] = el; __syncthreads();
      for (int st = 128; st > 0; st >>= 1) { if (tid < st) red[tid] += red[tid + st]; __syncthreads(); }
      float al = el / red[0];
      if (tid < 64) sm_al[tid] = (tid < ML) ? al : 0.f;
      __syncthreads();
      if (blockIdx.x == 0) {
        out[OUT_ATTOB + (long)s * NP + tid] = aop;
        if (tid < ML) out[OUT_ATTW + (long)s * ML + tid] = al;
      }
      // c1 rows {r0,r1}
      float4 a4 = *(const float4*)(&sm_aop[4 * lane]);
      const float* mp0 = ws + OFF_MPROP + (long)r0 * 256;
      const float* mp1 = ws + OFF_MPROP + (long)r1 * 256;
      float acc0 = dot4(*(const float4*)(mp0 + 4 * lane), a4);
      float acc1 = dot4(*(const float4*)(mp1 + 4 * lane), a4);
      if (lane < ML) {
        float alv = sm_al[lane];
        acc0 += ws[OFF_MENC + (long)r0 * ML + lane] * alv;
        acc1 += ws[OFF_MENC + (long)r1 * ML + lane] * alv;
      }
      acc0 = wred(acc0); acc1 = wred(acc1);
      if (lane == 0) {
        float v0 = acc0 + ws[OFF_PC + s * HDIM + r0];
        float v1 = acc1 + ws[OFF_PC + s * HDIM + r1];
        gstore(ws + OFF_C1 + r0, v0 > 0.f ? v0 : 0.f);
        gstore(ws + OFF_C1 + r1, v1 > 0.f ? v1 : 0.f);
      }
      gbar_arrive(ws, bar);
      // ---- gap work: prefetch wc2 rows for D ----
      const float* q0 = wc2 + (long)r0 * HDIM;
      const float* q1 = wc2 + (long)r1 * HDIM;
      wc0a = *(const float4*)(q0 + 4 * lane);
      wc0b = *(const float4*)(q0 + 256 + 4 * lane);
      wc1a = *(const float4*)(q1 + 4 * lane);
      wc1b = *(const float4*)(q1 + 256 + 4 * lane);
      gbar_wait(ws, bar); bar++;
    }
    // ---------- Phase D: g rows {r0,r1}; arrive; prefetch wih; wait ----------
    float4 wi0a, wi0b, wi1a, wi1b, wi2a, wi2b, wi3a, wi3b, wi4a, wi4b, wi5a, wi5b;
    {
      float4 ca = ld4c(ws + OFF_C1 + 4 * lane);
      float4 cb = ld4c(ws + OFF_C1 + 256 + 4 * lane);
      float acc0 = dot4(wc0a, ca) + dot4(wc0b, cb);
      float acc1 = dot4(wc1a, ca) + dot4(wc1b, cb);
      acc0 = wred(acc0); acc1 = wred(acc1);
      if (lane == 0) {
        float v0 = acc0 + bc2[r0];
        float v1 = acc1 + bc2[r1];
        gstore(ws + OFF_G + r0, v0 > 0.f ? v0 : 0.f);
        gstore(ws + OFF_G + r1, v1 > 0.f ? v1 : 0.f);
      }
      gbar_arrive(ws, bar);
      // ---- gap work: prefetch wih rows for E ----
      const float* p0 = wih + (long)r0 * HDIM;
      const float* p1 = wih + (long)(r0 + 512) * HDIM;
      const float* p2 = wih + (long)(r0 + 1024) * HDIM;
      const float* p3 = wih + (long)r1 * HDIM;
      const float* p4 = wih + (long)(r1 + 512) * HDIM;
      const float* p5 = wih + (long)(r1 + 1024) * HDIM;
      wi0a = *(const float4*)(p0 + 4 * lane); wi0b = *(const float4*)(p0 + 256 + 4 * lane);
      wi1a = *(const float4*)(p1 + 4 * lane); wi1b = *(const float4*)(p1 + 256 + 4 * lane);
      wi2a = *(const float4*)(p2 + 4 * lane); wi2b = *(const float4*)(p2 + 256 + 4 * lane);
      wi3a = *(const float4*)(p3 + 4 * lane); wi3b = *(const float4*)(p3 + 256 + 4 * lane);
      wi4a = *(const float4*)(p4 + 4 * lane); wi4b = *(const float4*)(p4 + 256 + 4 * lane);
      wi5a = *(const float4*)(p5 + 4 * lane); wi5b = *(const float4*)(p5 + 256 + 4 * lane);
      gbar_wait(ws, bar); bar++;
    }
    // ---------- Phase E: GRU rows {r0,r1} -> h_{s+1} ----------
    {
      float4 ga = ld4c(ws + OFF_G + 4 * lane);
      float4 gb = ld4c(ws + OFF_G + 256 + 4 * lane);
      float a0 = dot4(wi0a, ga) + dot4(wi0b, gb);
      float a1 = dot4(wi1a, ga) + dot4(wi1b, gb);
      float a2 = dot4(wi2a, ga) + dot4(wi2b, gb);
      float a3 = dot4(wi3a, ga) + dot4(wi3b, gb);
      float a4_ = dot4(wi4a, ga) + dot4(wi4b, gb);
      float a5 = dot4(wi5a, ga) + dot4(wi5b, gb);
      a0 = wred(a0); a1 = wred(a1); a2 = wred(a2);
      a3 = wred(a3); a4_ = wred(a4_); a5 = wred(a5);
      if (lane == 0) {
        float ir0 = a0 + bih[r0], iz0 = a1 + bih[512 + r0], in0 = a2 + bih[1024 + r0];
        float rg0 = 1.f / (1.f + expf(-(ir0 + ghr0)));
        float zg0 = 1.f / (1.f + expf(-(iz0 + ghz0)));
        float ng0 = tanhf(in0 + rg0 * ghn0);
        float hp0 = ld1c(ws + OFF_HS + s * HDIM + r0);
        gstore(ws + OFF_HS + (s + 1) * HDIM + r0, (1.f - zg0) * ng0 + zg0 * hp0);
        float ir1 = a3 + bih[r1], iz1 = a4_ + bih[512 + r1], in1 = a5 + bih[1024 + r1];
        float rg1 = 1.f / (1.f + expf(-(ir1 + ghr1)));
        float zg1 = 1.f / (1.f + expf(-(iz1 + ghz1)));
        float ng1 = tanhf(in1 + rg1 * ghn1);
        float hp1 = ld1c(ws + OFF_HS + s * HDIM + r1);
        gstore(ws + OFF_HS + (s + 1) * HDIM + r1, (1.f - zg1) * ng1 + zg1 * hp1);
      }
      gbar_arrive(ws, bar);
      gbar_wait(ws, bar); bar++;
    }
  }
}

// logits: LDS-tiled GEMM. 256 rows/block, k-chunks of 32, thread-owns-row.
// Swizzled wl layout: float offset WL(row,q) = q*1032 + 4*row
//  - reads (thread t, fixed q): lane-consecutive 16B -> conflict-free
//  - writes (row=f>>3,q=f&7): 16B slot (2q+row)&7 uniform over lanes -> conflict-free
#define WL(row, q) ((q) * 1032 + 4 * (row))
__global__ void __launch_bounds__(256) k_final2(const float* __restrict__ ow,
                                                const float* __restrict__ ob,
                                                const float* __restrict__ ws,
                                                float* __restrict__ out) {
  __shared__ __align__(16) float wl[8 * 1032];
  __shared__ __align__(16) float hl[T_STEPS * 512];
  int tid = threadIdx.x;
  long rbase = (long)blockIdx.x * 256;
  for (int i = tid; i < T_STEPS * 512; i += 256) hl[i] = ws[OFF_HS + 512 + i];
  float4 st[8];
  // prologue load chunk 0
#pragma unroll
  for (int i = 0; i < 8; ++i) {
    int f = tid + 256 * i; int row = f >> 3, q = f & 7;
    long r = rbase + row;
    st[i] = (r < V) ? *(const float4*)(ow + r * 512 + 4 * q) : make_float4(0.f, 0.f, 0.f, 0.f);
  }
  float acc[T_STEPS];
#pragma unroll
  for (int s = 0; s < T_STEPS; ++s) acc[s] = 0.f;
  __syncthreads();  // hl ready
  for (int c = 0; c < 16; ++c) {
    // write staged regs -> LDS (swizzled, conflict-free b128)
#pragma unroll
    for (int i = 0; i < 8; ++i) {
      int f = tid + 256 * i; int row = f >> 3, q = f & 7;
      *(float4*)(&wl[WL(row, q)]) = st[i];
    }
    __syncthreads();  // wl ready
    if (c < 15) {
#pragma unroll
      for (int i = 0; i < 8; ++i) {
        int f = tid + 256 * i; int row = f >> 3, q = f & 7;
        long r = rbase + row;
        st[i] = (r < V) ? *(const float4*)(ow + r * 512 + (c + 1) * 32 + 4 * q) : make_float4(0.f, 0.f, 0.f, 0.f);
      }
    }
    // compute: thread owns row=tid
#pragma unroll
    for (int kq = 0; kq < 8; ++kq) {
      float4 w4 = *(const float4*)(&wl[WL(tid, kq)]);
      const float* hb = hl + c * 32 + 4 * kq;
#pragma unroll
      for (int s = 0; s < T_STEPS; ++s) {
        float4 h4 = *(const float4*)(hb + s * 512);
        acc[s] += dot4(w4, h4);
      }
    }
    __syncthreads();  // done reading wl
  }
  long r = rbase + tid;
  if (r < V) {
    float b = ob[r];
#pragma unroll
    for (int s = 0; s < T_STEPS; ++s) out[OUT_LOGITS + (long)s * V + r] = acc[s] + b;
  }
}

extern "C" void kernel_launch(void* const* d_in, const int* in_sizes, int n_in,
                              void* d_out, int out_size, void* d_ws, size_t ws_size,
                              hipStream_t stream) {
  const int*   input_tok  = (const int*)d_in[0];
  const float* hidden     = (const float*)d_in[1];
  const float* enc        = (const float*)d_in[2];
  const float* prop       = (const float*)d_in[3];
  const int*   obj_mask   = (const int*)d_in[4];
  const int*   lang_mask  = (const int*)d_in[5];
  const int*   ans        = (const int*)d_in[6];
  const float* emb        = (const float*)d_in[7];
  const float* attn_w1    = (const float*)d_in[8];
  const float* attn_b1    = (const float*)d_in[9];
  const float* attn_w2    = (const float*)d_in[10];
  const float* attn_b2    = (const float*)d_in[11];
  const float* attn_op_w1 = (const float*)d_in[12];
  const float* attn_op_b1 = (const float*)d_in[13];
  const float* attn_op_w2 = (const float*)d_in[14];
  const float* attn_op_b2 = (const float*)d_in[15];
  const float* cmb_w1     = (const float*)d_in[16];
  const float* cmb_b1     = (const float*)d_in[17];
  const float* cmb_w2     = (const float*)d_in[18];
  const float* cmb_b2     = (const float*)d_in[19];
  const float* gw_ih      = (const float*)d_in[20];
  const float* gw_hh      = (const float*)d_in[21];
  const float* gb_ih      = (const float*)d_in[22];
  const float* gb_hh      = (const float*)d_in[23];
  const float* out_w      = (const float*)d_in[24];
  const float* out_b      = (const float*)d_in[25];
  float* out = (float*)d_out;
  float* ws  = (float*)d_ws;

  // reset the 64 barrier flags (monotonic; first barrier index is 1)
  hipMemsetAsync((char*)d_ws + (size_t)OFF_BAR * 4, 0, 8448, stream);
  k_pre1<<<25, 256, 0, stream>>>(input_tok, ans, emb, hidden, ws);
  k_pre2<<<4864, 256, 0, stream>>>(attn_op_w1, attn_op_b1, attn_w1, attn_b1, cmb_w1, cmb_b1, ws);
  k_mprep<<<512, 256, 0, stream>>>(cmb_w1, prop, enc, ws);
  k_pre4<<<256, 256, 0, stream>>>(attn_op_w2, attn_w2, ws);
  k_recur<<<NBLK, 256, 0, stream>>>(attn_op_w1, attn_w1, gw_hh, gb_hh,
                                    attn_op_b2, attn_b2,
                                    obj_mask, lang_mask, cmb_w2, cmb_b2,
                                    gw_ih, gb_ih, ws, out);
  k_final2<<<(V + 255) / 256, 256, 0, stream>>>(out_w, out_b, ws, out);
}

// Round 8
// 573.643 us; speedup vs baseline: 1.1715x; 1.1715x over previous
//
#include <hip/hip_runtime.h>
#include <math.h>

#define T_STEPS 19
#define V 50257
#define EMB 300
#define HDIM 512
#define NP 256
#define ML 50
#define CIN 812
#define NEGV -1e9f
#define NBLK 64

// ---- workspace layout (float indices) ----
// read-only-after-prep region:
#define OFF_X      0                         // 19*300 = 5700
#define OFF_POP    5700                      // 19*256
#define OFF_PL     10564                     // 19*256
#define OFF_PC     15428                     // 19*512
#define OFF_MPROP  25156                     // 512*256 = 131072
#define OFF_MENC   156228                    // 512*50  = 25600
// poisoned dataflow region (contiguous, memset 0xFF each launch):
#define OFF_HS     181828                    // 20*512 (HS[0] overwritten by k_pre1)
#define OFF_H1OP   192068                    // 19*256
#define OFF_H1L    196932                    // 19*256
#define OFF_LOGOP  201796                    // 19*256
#define OFF_LOGL   206660                    // 19*64
#define OFF_C1     207876                    // 19*512
#define OFF_G      217604                    // 19*512
#define POISON_END 227332
#define POISON_BYTES ((POISON_END - OFF_HS) * 4)

#define H1OP_S(s) (OFF_H1OP + (s) * 256)
#define H1L_S(s)  (OFF_H1L  + (s) * 256)
#define LOGOP_S(s)(OFF_LOGOP+ (s) * 256)
#define LOGL_S(s) (OFF_LOGL + (s) * 64)
#define C1_S(s)   (OFF_C1   + (s) * 512)
#define G_S(s)    (OFF_G    + (s) * 512)

// ---- output layout (floats) ----
#define OUT_LOGITS 0
#define OUT_ATTW   ((long)T_STEPS * V)
#define OUT_ATTOB  (OUT_ATTW + (long)T_STEPS * ML)

__device__ __forceinline__ float wred(float v) {
  v += __shfl_xor(v, 32, 64);
  v += __shfl_xor(v, 16, 64);
  v += __shfl_xor(v, 8, 64);
  v += __shfl_xor(v, 4, 64);
  v += __shfl_xor(v, 2, 64);
  v += __shfl_xor(v, 1, 64);
  return v;
}

__device__ __forceinline__ float dot4(float4 a, float4 b) {
  return a.x * b.x + a.y * b.y + a.z * b.z + a.w * b.w;
}

// ---- agent-coherent access (bypass non-coherent L1/L2; hit the MALL) ----
__device__ __forceinline__ void gstore(float* p, float v) {
  __hip_atomic_store(p, v, __ATOMIC_RELAXED, __HIP_MEMORY_SCOPE_AGENT);
}
__device__ __forceinline__ float ld1c(const float* p) {
  return __hip_atomic_load(p, __ATOMIC_RELAXED, __HIP_MEMORY_SCOPE_AGENT);
}
__device__ __forceinline__ float2 ld2c(const float* p) {
  unsigned long long u = __hip_atomic_load((const unsigned long long*)p,
                                           __ATOMIC_RELAXED, __HIP_MEMORY_SCOPE_AGENT);
  float2 r;
  r.x = __uint_as_float((unsigned)u);
  r.y = __uint_as_float((unsigned)(u >> 32));
  return r;
}
__device__ __forceinline__ float4 ld4c(const float* p) {
  float2 a = ld2c(p), b = ld2c(p + 2);
  return make_float4(a.x, a.y, b.x, b.y);
}

// ---- NaN-poison dataflow polling: wait until the exact consumed dwords are real ----
__device__ __forceinline__ int nan4(float4 v) {
  return (v.x != v.x) | (v.y != v.y) | (v.z != v.z) | (v.w != v.w);
}
__device__ __forceinline__ float4 poll4(const float* p) {
  float4 v = ld4c(p);
  while (__any(nan4(v))) { __builtin_amdgcn_s_sleep(1); v = ld4c(p); }
  return v;
}
__device__ __forceinline__ float poll1(const float* p) {
  float v = ld1c(p);
  while (__any(v != v)) { __builtin_amdgcn_s_sleep(1); v = ld1c(p); }
  return v;
}

// Precompute X = relu(emb[token]) for all steps; copy Hs[0].
__global__ void k_pre1(const int* __restrict__ tok0, const int* __restrict__ ans,
                       const float* __restrict__ emb, const float* __restrict__ hidden,
                       float* __restrict__ ws) {
  int tid = blockIdx.x * 256 + threadIdx.x;
  if (tid < T_STEPS * EMB) {
    int s = tid / EMB, j = tid - s * EMB;
    int t = (s == 0) ? tok0[0] : ans[s];
    float v = emb[(long)t * EMB + j];
    ws[OFF_X + tid] = v > 0.f ? v : 0.f;
  } else {
    int k = tid - T_STEPS * EMB;
    if (k < HDIM) ws[OFF_HS + k] = hidden[k];
  }
}

// P_op/P_l/P_c: x-column partials + layer-1 biases. wave-per-row, 19*1024 rows.
__global__ void k_pre2(const float* __restrict__ w1op, const float* __restrict__ b1op,
                       const float* __restrict__ w1l,  const float* __restrict__ b1l,
                       const float* __restrict__ wc1,  const float* __restrict__ bc1,
                       float* __restrict__ ws) {
  int gw = (blockIdx.x * 256 + threadIdx.x) >> 6;
  int lane = threadIdx.x & 63;
  int s = gw >> 10;
  int rr = gw & 1023;
  if (s >= T_STEPS) return;
  const float* wrow; const float* bias; float* dst; int r;
  if (rr < 256)      { r = rr;       wrow = w1op + (long)r * CIN; bias = b1op; dst = ws + OFF_POP + s * 256 + r; }
  else if (rr < 512) { r = rr - 256; wrow = w1l  + (long)r * CIN; bias = b1l;  dst = ws + OFF_PL  + s * 256 + r; }
  else               { r = rr - 512; wrow = wc1  + (long)r * CIN; bias = bc1;  dst = ws + OFF_PC  + s * 512 + r; }
  const float* x = ws + OFF_X + s * EMB;
  float acc = 0.f;
#pragma unroll
  for (int it = 0; it < 5; ++it) {
    int j = it * 64 + lane;
    if (j < EMB) acc += wrow[j] * x[j];
  }
  acc = wred(acc);
  if (lane == 0) *dst = acc + bias[r];
}

// M_prop[r][p] = sum_k cmb_w1[r][556+k]*prop[p][k]; M_enc[r][j] = sum_k cmb_w1[r][300+k]*enc[j][k]
#define LDSF 12850
__global__ void __launch_bounds__(256) k_mprep(const float* __restrict__ cw1,
                                               const float* __restrict__ prop,
                                               const float* __restrict__ enc,
                                               float* __restrict__ ws) {
  __shared__ float lds[LDSF];
  int tid = threadIdx.x, r = blockIdx.x;
  float acc = 0.f;
  for (int kc = 0; kc < 8; ++kc) {
    __syncthreads();
#pragma unroll
    for (int i = 0; i < 8; ++i) {
      int f = tid + 256 * i; int row = f >> 3, q = f & 7;
      float4 v = *(const float4*)(prop + (long)row * 256 + kc * 32 + 4 * q);
      float* p = lds + row * 33 + 4 * q;
      p[0] = v.x; p[1] = v.y; p[2] = v.z; p[3] = v.w;
    }
    __syncthreads();
    const float* wbase = cw1 + (long)r * CIN + 556 + kc * 32;
    const float* pl = lds + tid * 33;
#pragma unroll
    for (int k4 = 0; k4 < 8; ++k4) {
      float4 w4 = *(const float4*)(wbase + 4 * k4);
      const float* pp = pl + 4 * k4;
      acc += w4.x * pp[0] + w4.y * pp[1] + w4.z * pp[2] + w4.w * pp[3];
    }
  }
  ws[OFF_MPROP + (long)r * 256 + tid] = acc;
  __syncthreads();
  for (int i = 0; i < 13; ++i) {
    int f = tid + 256 * i;
    if (f < 3200) {
      int row = f >> 6, q = f & 63;
      float4 v = *(const float4*)(enc + (long)row * 256 + 4 * q);
      float* p = lds + row * 257 + 4 * q;
      p[0] = v.x; p[1] = v.y; p[2] = v.z; p[3] = v.w;
    }
  }
  __syncthreads();
  if (tid < ML) {
    const float* wb2 = cw1 + (long)r * CIN + 300;
    const float* el = lds + tid * 257;
    float a2 = 0.f;
#pragma unroll 8
    for (int k = 0; k < 256; ++k) a2 += wb2[k] * el[k];
    ws[OFF_MENC + (long)r * ML + tid] = a2;
  }
}

// Persistent fused recurrence: pure NaN-poison dataflow, NO grid barriers.
// 64 blocks x 256 threads = 256 waves; wave wv owns rows {2wv, 2wv+1}.
__global__ void __launch_bounds__(256) k_recur(
    const float* __restrict__ w1op, const float* __restrict__ w1l,
    const float* __restrict__ whh,  const float* __restrict__ bhh,
    const float* __restrict__ w2op, const float* __restrict__ b2op,
    const float* __restrict__ w2l,  const float* __restrict__ b2l,
    const int* __restrict__ obj_mask, const int* __restrict__ lang_mask,
    const float* __restrict__ wc2,  const float* __restrict__ bc2,
    const float* __restrict__ wih,  const float* __restrict__ bih,
    float* ws, float* __restrict__ out) {
  const int tid = threadIdx.x;
  const int lane = tid & 63;
  const int wv = (blockIdx.x << 2) + (tid >> 6);   // 0..255
  const int r0 = 2 * wv, r1 = 2 * wv + 1;          // owned rows 0..511
  __shared__ float red[256];
  __shared__ __align__(16) float sm_aop[256];
  __shared__ float sm_al[64];

  for (int s = 0; s < T_STEPS; ++s) {
    float ghr0, ghz0, ghn0, ghr1, ghz1, ghn1;  // GRU h-side partials (A -> E, same wave)
    // ---------- Phase A: poll h[s]; h1 rows {r0,r1}; gh -> regs ----------
    {
      const float* h = ws + OFF_HS + s * HDIM;
      float4 ha = poll4(h + 4 * lane);
      float4 hb = poll4(h + 256 + 4 * lane);
      const float* wa0 = (r0 < 256) ? (w1op + (long)r0 * CIN + 300) : (w1l + (long)(r0 - 256) * CIN + 300);
      const float* wa1 = (r1 < 256) ? (w1op + (long)r1 * CIN + 300) : (w1l + (long)(r1 - 256) * CIN + 300);
      float a0 = dot4(*(const float4*)(wa0 + 4 * lane), ha) + dot4(*(const float4*)(wa0 + 256 + 4 * lane), hb);
      float a1 = dot4(*(const float4*)(wa1 + 4 * lane), ha) + dot4(*(const float4*)(wa1 + 256 + 4 * lane), hb);
      const float* p0 = whh + (long)r0 * HDIM;
      const float* p1 = whh + (long)(r0 + 512) * HDIM;
      const float* p2 = whh + (long)(r0 + 1024) * HDIM;
      const float* p3 = whh + (long)r1 * HDIM;
      const float* p4 = whh + (long)(r1 + 512) * HDIM;
      const float* p5 = whh + (long)(r1 + 1024) * HDIM;
      float b0 = dot4(*(const float4*)(p0 + 4 * lane), ha) + dot4(*(const float4*)(p0 + 256 + 4 * lane), hb);
      float b1 = dot4(*(const float4*)(p1 + 4 * lane), ha) + dot4(*(const float4*)(p1 + 256 + 4 * lane), hb);
      float b2 = dot4(*(const float4*)(p2 + 4 * lane), ha) + dot4(*(const float4*)(p2 + 256 + 4 * lane), hb);
      float b3 = dot4(*(const float4*)(p3 + 4 * lane), ha) + dot4(*(const float4*)(p3 + 256 + 4 * lane), hb);
      float b4 = dot4(*(const float4*)(p4 + 4 * lane), ha) + dot4(*(const float4*)(p4 + 256 + 4 * lane), hb);
      float b5 = dot4(*(const float4*)(p5 + 4 * lane), ha) + dot4(*(const float4*)(p5 + 256 + 4 * lane), hb);
      a0 = wred(a0); a1 = wred(a1);
      b0 = wred(b0); b1 = wred(b1); b2 = wred(b2);
      b3 = wred(b3); b4 = wred(b4); b5 = wred(b5);
      ghr0 = b0 + bhh[r0]; ghz0 = b1 + bhh[512 + r0]; ghn0 = b2 + bhh[1024 + r0];
      ghr1 = b3 + bhh[r1]; ghz1 = b4 + bhh[512 + r1]; ghn1 = b5 + bhh[1024 + r1];
      if (lane == 0) {
        float v0 = a0 + ((r0 < 256) ? ws[OFF_POP + s * 256 + r0] : ws[OFF_PL + s * 256 + (r0 - 256)]);
        float v1 = a1 + ((r1 < 256) ? ws[OFF_POP + s * 256 + r1] : ws[OFF_PL + s * 256 + (r1 - 256)]);
        float* d0 = (r0 < 256) ? (ws + H1OP_S(s) + r0) : (ws + H1L_S(s) + (r0 - 256));
        float* d1 = (r1 < 256) ? (ws + H1OP_S(s) + r1) : (ws + H1L_S(s) + (r1 - 256));
        gstore(d0, v0 > 0.f ? v0 : 0.f);
        gstore(d1, v1 > 0.f ? v1 : 0.f);
      }
    }
    // ---------- Phase B: poll h1; attention logits (op row wv; lang row wv if wv<50) ----------
    {
      float4 h1 = poll4(ws + H1OP_S(s) + 4 * lane);
      const float* wr = w2op + (long)wv * 256;
      float acc = wred(dot4(*(const float4*)(wr + 4 * lane), h1));
      if (lane == 0) gstore(ws + LOGOP_S(s) + wv, acc + b2op[wv]);
      if (wv < ML) {
        float4 h1l = poll4(ws + H1L_S(s) + 4 * lane);
        const float* wrl = w2l + (long)wv * 256;
        float accl = wred(dot4(*(const float4*)(wrl + 4 * lane), h1l));
        if (lane == 0) gstore(ws + LOGL_S(s) + wv, accl + b2l[wv]);
      }
    }
    // ---------- Phase C: poll logits; block-redundant softmax + c1 rows {r0,r1} ----------
    {
      float lv = poll1(ws + LOGOP_S(s) + tid);
      float vo = (obj_mask[tid] != 0) ? NEGV : lv;
      red[tid] = vo; __syncthreads();
      for (int st = 128; st > 0; st >>= 1) { if (tid < st) red[tid] = fmaxf(red[tid], red[tid + st]); __syncthreads(); }
      float mo = red[0]; __syncthreads();
      float eo = expf(vo - mo);
      red[tid] = eo; __syncthreads();
      for (int st = 128; st > 0; st >>= 1) { if (tid < st) red[tid] += red[tid + st]; __syncthreads(); }
      float aop = eo / red[0];
      sm_aop[tid] = aop;
      __syncthreads();
      float ll = 0.f;
      if (tid < ML) ll = poll1(ws + LOGL_S(s) + tid);
      float vl = (tid < ML) ? ((lang_mask[tid] != 0) ? NEGV : ll) : -3e38f;
      red[tid] = vl; __syncthreads();
      for (int st = 128; st > 0; st >>= 1) { if (tid < st) red[tid] = fmaxf(red[tid], red[tid + st]); __syncthreads(); }
      float ml_ = red[0]; __syncthreads();
      float el = (tid < ML) ? expf(vl - ml_) : 0.f;
      red[tid] = el; __syncthreads();
      for (int st = 128; st > 0; st >>= 1) { if (tid < st) red[tid] += red[tid + st]; __syncthreads(); }
      float al = el / red[0];
      if (tid < 64) sm_al[tid] = (tid < ML) ? al : 0.f;
      __syncthreads();
      if (blockIdx.x == 0) {
        out[OUT_ATTOB + (long)s * NP + tid] = aop;
        if (tid < ML) out[OUT_ATTW + (long)s * ML + tid] = al;
      }
      float4 a4 = *(const float4*)(&sm_aop[4 * lane]);
      const float* mp0 = ws + OFF_MPROP + (long)r0 * 256;
      const float* mp1 = ws + OFF_MPROP + (long)r1 * 256;
      float acc0 = dot4(*(const float4*)(mp0 + 4 * lane), a4);
      float acc1 = dot4(*(const float4*)(mp1 + 4 * lane), a4);
      if (lane < ML) {
        float alv = sm_al[lane];
        acc0 += ws[OFF_MENC + (long)r0 * ML + lane] * alv;
        acc1 += ws[OFF_MENC + (long)r1 * ML + lane] * alv;
      }
      acc0 = wred(acc0); acc1 = wred(acc1);
      if (lane == 0) {
        float v0 = acc0 + ws[OFF_PC + s * HDIM + r0];
        float v1 = acc1 + ws[OFF_PC + s * HDIM + r1];
        gstore(ws + C1_S(s) + r0, v0 > 0.f ? v0 : 0.f);
        gstore(ws + C1_S(s) + r1, v1 > 0.f ? v1 : 0.f);
      }
    }
    // ---------- Phase D: poll c1; g rows {r0,r1} ----------
    {
      float4 ca = poll4(ws + C1_S(s) + 4 * lane);
      float4 cb = poll4(ws + C1_S(s) + 256 + 4 * lane);
      const float* q0 = wc2 + (long)r0 * HDIM;
      const float* q1 = wc2 + (long)r1 * HDIM;
      float acc0 = dot4(*(const float4*)(q0 + 4 * lane), ca) + dot4(*(const float4*)(q0 + 256 + 4 * lane), cb);
      float acc1 = dot4(*(const float4*)(q1 + 4 * lane), ca) + dot4(*(const float4*)(q1 + 256 + 4 * lane), cb);
      acc0 = wred(acc0); acc1 = wred(acc1);
      if (lane == 0) {
        float v0 = acc0 + bc2[r0];
        float v1 = acc1 + bc2[r1];
        gstore(ws + G_S(s) + r0, v0 > 0.f ? v0 : 0.f);
        gstore(ws + G_S(s) + r1, v1 > 0.f ? v1 : 0.f);
      }
    }
    // ---------- Phase E: poll g; GRU rows {r0,r1} -> h_{s+1} ----------
    {
      float4 ga = poll4(ws + G_S(s) + 4 * lane);
      float4 gb = poll4(ws + G_S(s) + 256 + 4 * lane);
      const float* p0 = wih + (long)r0 * HDIM;
      const float* p1 = wih + (long)(r0 + 512) * HDIM;
      const float* p2 = wih + (long)(r0 + 1024) * HDIM;
      const float* p3 = wih + (long)r1 * HDIM;
      const float* p4 = wih + (long)(r1 + 512) * HDIM;
      const float* p5 = wih + (long)(r1 + 1024) * HDIM;
      float a0 = dot4(*(const float4*)(p0 + 4 * lane), ga) + dot4(*(const float4*)(p0 + 256 + 4 * lane), gb);
      float a1 = dot4(*(const float4*)(p1 + 4 * lane), ga) + dot4(*(const float4*)(p1 + 256 + 4 * lane), gb);
      float a2 = dot4(*(const float4*)(p2 + 4 * lane), ga) + dot4(*(const float4*)(p2 + 256 + 4 * lane), gb);
      float a3 = dot4(*(const float4*)(p3 + 4 * lane), ga) + dot4(*(const float4*)(p3 + 256 + 4 * lane), gb);
      float a4_ = dot4(*(const float4*)(p4 + 4 * lane), ga) + dot4(*(const float4*)(p4 + 256 + 4 * lane), gb);
      float a5 = dot4(*(const float4*)(p5 + 4 * lane), ga) + dot4(*(const float4*)(p5 + 256 + 4 * lane), gb);
      a0 = wred(a0); a1 = wred(a1); a2 = wred(a2);
      a3 = wred(a3); a4_ = wred(a4_); a5 = wred(a5);
      if (lane == 0) {
        float ir0 = a0 + bih[r0], iz0 = a1 + bih[512 + r0], in0 = a2 + bih[1024 + r0];
        float rg0 = 1.f / (1.f + expf(-(ir0 + ghr0)));
        float zg0 = 1.f / (1.f + expf(-(iz0 + ghz0)));
        float ng0 = tanhf(in0 + rg0 * ghn0);
        float hp0 = ld1c(ws + OFF_HS + s * HDIM + r0);
        gstore(ws + OFF_HS + (s + 1) * HDIM + r0, (1.f - zg0) * ng0 + zg0 * hp0);
        float ir1 = a3 + bih[r1], iz1 = a4_ + bih[512 + r1], in1 = a5 + bih[1024 + r1];
        float rg1 = 1.f / (1.f + expf(-(ir1 + ghr1)));
        float zg1 = 1.f / (1.f + expf(-(iz1 + ghz1)));
        float ng1 = tanhf(in1 + rg1 * ghn1);
        float hp1 = ld1c(ws + OFF_HS + s * HDIM + r1);
        gstore(ws + OFF_HS + (s + 1) * HDIM + r1, (1.f - zg1) * ng1 + zg1 * hp1);
      }
    }
  }
}

// logits: LDS-tiled GEMM. 256 rows/block, k-chunks of 32, thread-owns-row.
// Swizzled wl layout WL(row,q)=q*1032+4*row: reads are contiguous 1KB/wave
// (conflict-free); writes are <=2-way (free per m136).
#define WL(row, q) ((q) * 1032 + 4 * (row))
__global__ void __launch_bounds__(256) k_final2(const float* __restrict__ ow,
                                                const float* __restrict__ ob,
                                                const float* __restrict__ ws,
                                                float* __restrict__ out) {
  __shared__ __align__(16) float wl[8 * 1032];
  __shared__ __align__(16) float hl[T_STEPS * 512];
  int tid = threadIdx.x;
  long rbase = (long)blockIdx.x * 256;
  for (int i = tid; i < T_STEPS * 512; i += 256) hl[i] = ws[OFF_HS + 512 + i];
  float4 st[8];
#pragma unroll
  for (int i = 0; i < 8; ++i) {
    int f = tid + 256 * i; int row = f >> 3, q = f & 7;
    long r = rbase + row;
    st[i] = (r < V) ? *(const float4*)(ow + r * 512 + 4 * q) : make_float4(0.f, 0.f, 0.f, 0.f);
  }
  float acc[T_STEPS];
#pragma unroll
  for (int s = 0; s < T_STEPS; ++s) acc[s] = 0.f;
  __syncthreads();
  for (int c = 0; c < 16; ++c) {
#pragma unroll
    for (int i = 0; i < 8; ++i) {
      int f = tid + 256 * i; int row = f >> 3, q = f & 7;
      *(float4*)(&wl[WL(row, q)]) = st[i];
    }
    __syncthreads();
    if (c < 15) {
#pragma unroll
      for (int i = 0; i < 8; ++i) {
        int f = tid + 256 * i; int row = f >> 3, q = f & 7;
        long r = rbase + row;
        st[i] = (r < V) ? *(const float4*)(ow + r * 512 + (c + 1) * 32 + 4 * q) : make_float4(0.f, 0.f, 0.f, 0.f);
      }
    }
#pragma unroll
    for (int kq = 0; kq < 8; ++kq) {
      float4 w4 = *(const float4*)(&wl[WL(tid, kq)]);
      const float* hb = hl + c * 32 + 4 * kq;
#pragma unroll
      for (int s = 0; s < T_STEPS; ++s) {
        float4 h4 = *(const float4*)(hb + s * 512);
        acc[s] += dot4(w4, h4);
      }
    }
    __syncthreads();
  }
  long r = rbase + tid;
  if (r < V) {
    float b = ob[r];
#pragma unroll
    for (int s = 0; s < T_STEPS; ++s) out[OUT_LOGITS + (long)s * V + r] = acc[s] + b;
  }
}

extern "C" void kernel_launch(void* const* d_in, const int* in_sizes, int n_in,
                              void* d_out, int out_size, void* d_ws, size_t ws_size,
                              hipStream_t stream) {
  const int*   input_tok  = (const int*)d_in[0];
  const float* hidden     = (const float*)d_in[1];
  const float* enc        = (const float*)d_in[2];
  const float* prop       = (const float*)d_in[3];
  const int*   obj_mask   = (const int*)d_in[4];
  const int*   lang_mask  = (const int*)d_in[5];
  const int*   ans        = (const int*)d_in[6];
  const float* emb        = (const float*)d_in[7];
  const float* attn_w1    = (const float*)d_in[8];
  const float* attn_b1    = (const float*)d_in[9];
  const float* attn_w2    = (const float*)d_in[10];
  const float* attn_b2    = (const float*)d_in[11];
  const float* attn_op_w1 = (const float*)d_in[12];
  const float* attn_op_b1 = (const float*)d_in[13];
  const float* attn_op_w2 = (const float*)d_in[14];
  const float* attn_op_b2 = (const float*)d_in[15];
  const float* cmb_w1     = (const float*)d_in[16];
  const float* cmb_b1     = (const float*)d_in[17];
  const float* cmb_w2     = (const float*)d_in[18];
  const float* cmb_b2     = (const float*)d_in[19];
  const float* gw_ih      = (const float*)d_in[20];
  const float* gw_hh      = (const float*)d_in[21];
  const float* gb_ih      = (const float*)d_in[22];
  const float* gb_hh      = (const float*)d_in[23];
  const float* out_w      = (const float*)d_in[24];
  const float* out_b      = (const float*)d_in[25];
  float* out = (float*)d_out;
  float* ws  = (float*)d_ws;

  // Poison the entire dataflow region (all-NaN). Producers overwrite; consumers
  // poll for non-NaN. Done every launch (harness does not re-poison).
  hipMemsetAsync((char*)d_ws + (size_t)OFF_HS * 4, 0xFF, POISON_BYTES, stream);
  k_pre1<<<25, 256, 0, stream>>>(input_tok, ans, emb, hidden, ws);
  k_pre2<<<4864, 256, 0, stream>>>(attn_op_w1, attn_op_b1, attn_w1, attn_b1, cmb_w1, cmb_b1, ws);
  k_mprep<<<512, 256, 0, stream>>>(cmb_w1, prop, enc, ws);
  k_recur<<<NBLK, 256, 0, stream>>>(attn_op_w1, attn_w1, gw_hh, gb_hh,
                                    attn_op_w2, attn_op_b2, attn_w2, attn_b2,
                                    obj_mask, lang_mask, cmb_w2, cmb_b2,
                                    gw_ih, gb_ih, ws, out);
  k_final2<<<(V + 255) / 256, 256, 0, stream>>>(out_w, out_b, ws, out);
}

// Round 9
// 412.410 us; speedup vs baseline: 1.6295x; 1.3910x over previous
//
#include <hip/hip_runtime.h>
#include <math.h>

#define T_STEPS 19
#define V 50257
#define EMB 300
#define HDIM 512
#define NP 256
#define ML 50
#define CIN 812
#define NEGV -1e9f
#define NBLK 64

// ---- workspace layout (float indices) ----
#define OFF_X      0                         // 19*300 = 5700
#define OFF_POP    5700                      // 19*256
#define OFF_PL     10564                     // 19*256
#define OFF_PC     15428                     // 19*512
#define OFF_HS     25156                     // 20*512
#define OFF_H1OP   35396                     // 256
#define OFF_H1L    35652                     // 256
#define OFF_C1     35908                     // 512
#define OFF_G      36420                     // 512
#define OFF_LOGOP  36932                     // 256
#define OFF_LOGL   37188                     // 64
#define OFF_MPROP  37252                     // 512*256 = 131072
#define OFF_MENC   168324                    // 512*50  = 25600
#define OFF_BAR    193924                    // flags @ +16 + 16*b (64B stride)

// ---- output layout (floats) ----
#define OUT_LOGITS 0
#define OUT_ATTW   ((long)T_STEPS * V)
#define OUT_ATTOB  (OUT_ATTW + (long)T_STEPS * ML)

__device__ __forceinline__ float wred(float v) {
  v += __shfl_xor(v, 32, 64);
  v += __shfl_xor(v, 16, 64);
  v += __shfl_xor(v, 8, 64);
  v += __shfl_xor(v, 4, 64);
  v += __shfl_xor(v, 2, 64);
  v += __shfl_xor(v, 1, 64);
  return v;
}

__device__ __forceinline__ float dot4(float4 a, float4 b) {
  return a.x * b.x + a.y * b.y + a.z * b.z + a.w * b.w;
}

// ---- agent-coherent access (bypass non-coherent L1/L2; hit the MALL) ----
__device__ __forceinline__ void gstore(float* p, float v) {
  __hip_atomic_store(p, v, __ATOMIC_RELAXED, __HIP_MEMORY_SCOPE_AGENT);
}
__device__ __forceinline__ float ld1c(const float* p) {
  return __hip_atomic_load(p, __ATOMIC_RELAXED, __HIP_MEMORY_SCOPE_AGENT);
}
__device__ __forceinline__ float2 ld2c(const float* p) {
  unsigned long long u = __hip_atomic_load((const unsigned long long*)p,
                                           __ATOMIC_RELAXED, __HIP_MEMORY_SCOPE_AGENT);
  float2 r;
  r.x = __uint_as_float((unsigned)u);
  r.y = __uint_as_float((unsigned)(u >> 32));
  return r;
}
__device__ __forceinline__ float4 ld4c(const float* p) {
  float2 a = ld2c(p), b = ld2c(p + 2);
  return make_float4(a.x, a.y, b.x, b.y);
}

// All-poll-all fence-free grid barrier (proven R6): each block stores its flag;
// every block's wave-0 lanes poll all 64 flags directly at the MALL.
__device__ __forceinline__ void gbar(float* wsb, unsigned bar) {
  asm volatile("s_waitcnt vmcnt(0)" ::: "memory");
  __syncthreads();
  unsigned* flags = (unsigned*)(wsb + OFF_BAR) + 16;
  if (threadIdx.x == 0) {
    __hip_atomic_store(flags + 16 * blockIdx.x, bar, __ATOMIC_RELAXED, __HIP_MEMORY_SCOPE_AGENT);
  }
  asm volatile("" ::: "memory");
  if (threadIdx.x < 64) {
    unsigned* f = flags + 16 * threadIdx.x;
    while (__hip_atomic_load(f, __ATOMIC_RELAXED, __HIP_MEMORY_SCOPE_AGENT) < bar) {
      __builtin_amdgcn_s_sleep(1);
    }
  }
  __syncthreads();
}

// Precompute X = relu(emb[token]) for all steps; copy Hs[0].
__global__ void k_pre1(const int* __restrict__ tok0, const int* __restrict__ ans,
                       const float* __restrict__ emb, const float* __restrict__ hidden,
                       float* __restrict__ ws) {
  int tid = blockIdx.x * 256 + threadIdx.x;
  if (tid < T_STEPS * EMB) {
    int s = tid / EMB, j = tid - s * EMB;
    int t = (s == 0) ? tok0[0] : ans[s];
    float v = emb[(long)t * EMB + j];
    ws[OFF_X + tid] = v > 0.f ? v : 0.f;
  } else {
    int k = tid - T_STEPS * EMB;
    if (k < HDIM) ws[OFF_HS + k] = hidden[k];
  }
}

// P_op/P_l/P_c: x-column partials + layer-1 biases. wave-per-row, 19*1024 rows.
__global__ void k_pre2(const float* __restrict__ w1op, const float* __restrict__ b1op,
                       const float* __restrict__ w1l,  const float* __restrict__ b1l,
                       const float* __restrict__ wc1,  const float* __restrict__ bc1,
                       float* __restrict__ ws) {
  int gw = (blockIdx.x * 256 + threadIdx.x) >> 6;
  int lane = threadIdx.x & 63;
  int s = gw >> 10;
  int rr = gw & 1023;
  if (s >= T_STEPS) return;
  const float* wrow; const float* bias; float* dst; int r;
  if (rr < 256)      { r = rr;       wrow = w1op + (long)r * CIN; bias = b1op; dst = ws + OFF_POP + s * 256 + r; }
  else if (rr < 512) { r = rr - 256; wrow = w1l  + (long)r * CIN; bias = b1l;  dst = ws + OFF_PL  + s * 256 + r; }
  else               { r = rr - 512; wrow = wc1  + (long)r * CIN; bias = bc1;  dst = ws + OFF_PC  + s * 512 + r; }
  const float* x = ws + OFF_X + s * EMB;
  float acc = 0.f;
#pragma unroll
  for (int it = 0; it < 5; ++it) {
    int j = it * 64 + lane;
    if (j < EMB) acc += wrow[j] * x[j];
  }
  acc = wred(acc);
  if (lane == 0) *dst = acc + bias[r];
}

// M_prop[r][p] = sum_k cmb_w1[r][556+k]*prop[p][k]; M_enc[r][j] = sum_k cmb_w1[r][300+k]*enc[j][k]
#define LDSF 12850
__global__ void __launch_bounds__(256) k_mprep(const float* __restrict__ cw1,
                                               const float* __restrict__ prop,
                                               const float* __restrict__ enc,
                                               float* __restrict__ ws) {
  __shared__ float lds[LDSF];
  int tid = threadIdx.x, r = blockIdx.x;
  float acc = 0.f;
  for (int kc = 0; kc < 8; ++kc) {
    __syncthreads();
#pragma unroll
    for (int i = 0; i < 8; ++i) {
      int f = tid + 256 * i; int row = f >> 3, q = f & 7;
      float4 v = *(const float4*)(prop + (long)row * 256 + kc * 32 + 4 * q);
      float* p = lds + row * 33 + 4 * q;
      p[0] = v.x; p[1] = v.y; p[2] = v.z; p[3] = v.w;
    }
    __syncthreads();
    const float* wbase = cw1 + (long)r * CIN + 556 + kc * 32;
    const float* pl = lds + tid * 33;
#pragma unroll
    for (int k4 = 0; k4 < 8; ++k4) {
      float4 w4 = *(const float4*)(wbase + 4 * k4);
      const float* pp = pl + 4 * k4;
      acc += w4.x * pp[0] + w4.y * pp[1] + w4.z * pp[2] + w4.w * pp[3];
    }
  }
  ws[OFF_MPROP + (long)r * 256 + tid] = acc;
  __syncthreads();
  for (int i = 0; i < 13; ++i) {
    int f = tid + 256 * i;
    if (f < 3200) {
      int row = f >> 6, q = f & 63;
      float4 v = *(const float4*)(enc + (long)row * 256 + 4 * q);
      float* p = lds + row * 257 + 4 * q;
      p[0] = v.x; p[1] = v.y; p[2] = v.z; p[3] = v.w;
    }
  }
  __syncthreads();
  if (tid < ML) {
    const float* wb2 = cw1 + (long)r * CIN + 300;
    const float* el = lds + tid * 257;
    float a2 = 0.f;
#pragma unroll 8
    for (int k = 0; k < 256; ++k) a2 += wb2[k] * el[k];
    ws[OFF_MENC + (long)r * ML + tid] = a2;
  }
}

// Persistent fused recurrence, ALL step-invariant weights in registers.
// 64 blocks x 256 threads = 256 waves; wave wv owns rows {2wv, 2wv+1}.
__global__ void __launch_bounds__(256, 1) k_recur(
    const float* __restrict__ w1op, const float* __restrict__ w1l,
    const float* __restrict__ whh,  const float* __restrict__ bhh,
    const float* __restrict__ w2op, const float* __restrict__ b2op,
    const float* __restrict__ w2l,  const float* __restrict__ b2l,
    const int* __restrict__ obj_mask, const int* __restrict__ lang_mask,
    const float* __restrict__ wc2,  const float* __restrict__ bc2,
    const float* __restrict__ wih,  const float* __restrict__ bih,
    float* ws, float* __restrict__ out) {
  const int tid = threadIdx.x;
  const int lane = tid & 63;
  const int wv = (blockIdx.x << 2) + (tid >> 6);   // 0..255
  const int r0 = 2 * wv, r1 = 2 * wv + 1;          // owned rows 0..511
  const int l4 = 4 * lane;
  unsigned bar = 1;
  __shared__ float red[256];
  __shared__ __align__(16) float sm_aop[256];
  __shared__ float sm_al[64];

  // ---- one-time register preload of step-invariant weight slices ----
  const float* wa0p = (r0 < 256) ? (w1op + (long)r0 * CIN + 300) : (w1l + (long)(r0 - 256) * CIN + 300);
  const float* wa1p = (r1 < 256) ? (w1op + (long)r1 * CIN + 300) : (w1l + (long)(r1 - 256) * CIN + 300);
  float4 WA00 = *(const float4*)(wa0p + l4), WA01 = *(const float4*)(wa0p + 256 + l4);
  float4 WA10 = *(const float4*)(wa1p + l4), WA11 = *(const float4*)(wa1p + 256 + l4);
  const float* q;
  q = whh + (long)r0 * HDIM;           float4 WH00 = *(const float4*)(q + l4), WH01 = *(const float4*)(q + 256 + l4);
  q = whh + (long)(r0 + 512) * HDIM;   float4 WH10 = *(const float4*)(q + l4), WH11 = *(const float4*)(q + 256 + l4);
  q = whh + (long)(r0 + 1024) * HDIM;  float4 WH20 = *(const float4*)(q + l4), WH21 = *(const float4*)(q + 256 + l4);
  q = whh + (long)r1 * HDIM;           float4 WH30 = *(const float4*)(q + l4), WH31 = *(const float4*)(q + 256 + l4);
  q = whh + (long)(r1 + 512) * HDIM;   float4 WH40 = *(const float4*)(q + l4), WH41 = *(const float4*)(q + 256 + l4);
  q = whh + (long)(r1 + 1024) * HDIM;  float4 WH50 = *(const float4*)(q + l4), WH51 = *(const float4*)(q + 256 + l4);
  float4 W2  = *(const float4*)(w2op + (long)wv * 256 + l4);
  float4 W2L = (wv < ML) ? *(const float4*)(w2l + (long)wv * 256 + l4) : make_float4(0.f, 0.f, 0.f, 0.f);
  float4 MP0 = *(const float4*)(ws + OFF_MPROP + (long)r0 * 256 + l4);
  float4 MP1 = *(const float4*)(ws + OFF_MPROP + (long)r1 * 256 + l4);
  float  ME0 = (lane < ML) ? ws[OFF_MENC + (long)r0 * ML + lane] : 0.f;
  float  ME1 = (lane < ML) ? ws[OFF_MENC + (long)r1 * ML + lane] : 0.f;
  q = wc2 + (long)r0 * HDIM;           float4 WC00 = *(const float4*)(q + l4), WC01 = *(const float4*)(q + 256 + l4);
  q = wc2 + (long)r1 * HDIM;           float4 WC10 = *(const float4*)(q + l4), WC11 = *(const float4*)(q + 256 + l4);
  q = wih + (long)r0 * HDIM;           float4 WI00 = *(const float4*)(q + l4), WI01 = *(const float4*)(q + 256 + l4);
  q = wih + (long)(r0 + 512) * HDIM;   float4 WI10 = *(const float4*)(q + l4), WI11 = *(const float4*)(q + 256 + l4);
  q = wih + (long)(r0 + 1024) * HDIM;  float4 WI20 = *(const float4*)(q + l4), WI21 = *(const float4*)(q + 256 + l4);
  q = wih + (long)r1 * HDIM;           float4 WI30 = *(const float4*)(q + l4), WI31 = *(const float4*)(q + 256 + l4);
  q = wih + (long)(r1 + 512) * HDIM;   float4 WI40 = *(const float4*)(q + l4), WI41 = *(const float4*)(q + 256 + l4);
  q = wih + (long)(r1 + 1024) * HDIM;  float4 WI50 = *(const float4*)(q + l4), WI51 = *(const float4*)(q + 256 + l4);
  float BH0 = bhh[r0], BH1 = bhh[512 + r0], BH2 = bhh[1024 + r0];
  float BH3 = bhh[r1], BH4 = bhh[512 + r1], BH5 = bhh[1024 + r1];
  float BI0 = bih[r0], BI1 = bih[512 + r0], BI2 = bih[1024 + r0];
  float BI3 = bih[r1], BI4 = bih[512 + r1], BI5 = bih[1024 + r1];
  float BC0 = bc2[r0], BC1 = bc2[r1];
  float B2  = b2op[wv];
  float B2Lv = (wv < ML) ? b2l[wv] : 0.f;

  for (int s = 0; s < T_STEPS; ++s) {
    float ghr0, ghz0, ghn0, ghr1, ghz1, ghn1;
    // ---------- Phase A: h1 rows {r0,r1}; gh -> regs ----------
    {
      const float* h = ws + OFF_HS + s * HDIM;
      float4 ha = ld4c(h + l4);
      float4 hb = ld4c(h + 256 + l4);
      float a0 = dot4(WA00, ha) + dot4(WA01, hb);
      float a1 = dot4(WA10, ha) + dot4(WA11, hb);
      float b0 = dot4(WH00, ha) + dot4(WH01, hb);
      float b1 = dot4(WH10, ha) + dot4(WH11, hb);
      float b2 = dot4(WH20, ha) + dot4(WH21, hb);
      float b3 = dot4(WH30, ha) + dot4(WH31, hb);
      float b4 = dot4(WH40, ha) + dot4(WH41, hb);
      float b5 = dot4(WH50, ha) + dot4(WH51, hb);
      a0 = wred(a0); a1 = wred(a1);
      b0 = wred(b0); b1 = wred(b1); b2 = wred(b2);
      b3 = wred(b3); b4 = wred(b4); b5 = wred(b5);
      ghr0 = b0 + BH0; ghz0 = b1 + BH1; ghn0 = b2 + BH2;
      ghr1 = b3 + BH3; ghz1 = b4 + BH4; ghn1 = b5 + BH5;
      if (lane == 0) {
        float v0 = a0 + ((r0 < 256) ? ws[OFF_POP + s * 256 + r0] : ws[OFF_PL + s * 256 + (r0 - 256)]);
        float v1 = a1 + ((r1 < 256) ? ws[OFF_POP + s * 256 + r1] : ws[OFF_PL + s * 256 + (r1 - 256)]);
        float* d0 = (r0 < 256) ? (ws + OFF_H1OP + r0) : (ws + OFF_H1L + (r0 - 256));
        float* d1 = (r1 < 256) ? (ws + OFF_H1OP + r1) : (ws + OFF_H1L + (r1 - 256));
        gstore(d0, v0 > 0.f ? v0 : 0.f);
        gstore(d1, v1 > 0.f ? v1 : 0.f);
      }
    }
    gbar(ws, bar++);
    // ---------- Phase B: attention logits ----------
    {
      float4 h1 = ld4c(ws + OFF_H1OP + l4);
      float acc = wred(dot4(W2, h1));
      if (lane == 0) gstore(ws + OFF_LOGOP + wv, acc + B2);
      if (wv < ML) {
        float4 h1l = ld4c(ws + OFF_H1L + l4);
        float accl = wred(dot4(W2L, h1l));
        if (lane == 0) gstore(ws + OFF_LOGL + wv, accl + B2Lv);
      }
    }
    gbar(ws, bar++);
    // ---------- Phase C: block-redundant softmax + c1 rows {r0,r1} ----------
    {
      float lv = ld1c(ws + OFF_LOGOP + tid);
      float vo = (obj_mask[tid] != 0) ? NEGV : lv;
      red[tid] = vo; __syncthreads();
      for (int st = 128; st > 0; st >>= 1) { if (tid < st) red[tid] = fmaxf(red[tid], red[tid + st]); __syncthreads(); }
      float mo = red[0]; __syncthreads();
      float eo = expf(vo - mo);
      red[tid] = eo; __syncthreads();
      for (int st = 128; st > 0; st >>= 1) { if (tid < st) red[tid] += red[tid + st]; __syncthreads(); }
      float aop = eo / red[0];
      sm_aop[tid] = aop;
      __syncthreads();
      float ll = 0.f;
      if (tid < ML) ll = ld1c(ws + OFF_LOGL + tid);
      float vl = (tid < ML) ? ((lang_mask[tid] != 0) ? NEGV : ll) : -3e38f;
      red[tid] = vl; __syncthreads();
      for (int st = 128; st > 0; st >>= 1) { if (tid < st) red[tid] = fmaxf(red[tid], red[tid + st]); __syncthreads(); }
      float ml_ = red[0]; __syncthreads();
      float el = (tid < ML) ? expf(vl - ml_) : 0.f;
      red[tid] = el; __syncthreads();
      for (int st = 128; st > 0; st >>= 1) { if (tid < st) red[tid] += red[tid + st]; __syncthreads(); }
      float al = el / red[0];
      if (tid < 64) sm_al[tid] = (tid < ML) ? al : 0.f;
      __syncthreads();
      if (blockIdx.x == 0) {
        out[OUT_ATTOB + (long)s * NP + tid] = aop;
        if (tid < ML) out[OUT_ATTW + (long)s * ML + tid] = al;
      }
      float4 a4 = *(const float4*)(&sm_aop[l4]);
      float acc0 = dot4(MP0, a4);
      float acc1 = dot4(MP1, a4);
      if (lane < ML) {
        float alv = sm_al[lane];
        acc0 += ME0 * alv;
        acc1 += ME1 * alv;
      }
      acc0 = wred(acc0); acc1 = wred(acc1);
      if (lane == 0) {
        float v0 = acc0 + ws[OFF_PC + s * HDIM + r0];
        float v1 = acc1 + ws[OFF_PC + s * HDIM + r1];
        gstore(ws + OFF_C1 + r0, v0 > 0.f ? v0 : 0.f);
        gstore(ws + OFF_C1 + r1, v1 > 0.f ? v1 : 0.f);
      }
    }
    gbar(ws, bar++);
    // ---------- Phase D: g rows {r0,r1} ----------
    {
      float4 ca = ld4c(ws + OFF_C1 + l4);
      float4 cb = ld4c(ws + OFF_C1 + 256 + l4);
      float acc0 = dot4(WC00, ca) + dot4(WC01, cb);
      float acc1 = dot4(WC10, ca) + dot4(WC11, cb);
      acc0 = wred(acc0); acc1 = wred(acc1);
      if (lane == 0) {
        float v0 = acc0 + BC0;
        float v1 = acc1 + BC1;
        gstore(ws + OFF_G + r0, v0 > 0.f ? v0 : 0.f);
        gstore(ws + OFF_G + r1, v1 > 0.f ? v1 : 0.f);
      }
    }
    gbar(ws, bar++);
    // ---------- Phase E: GRU rows {r0,r1} -> h_{s+1} ----------
    {
      float4 ga = ld4c(ws + OFF_G + l4);
      float4 gb = ld4c(ws + OFF_G + 256 + l4);
      float a0 = dot4(WI00, ga) + dot4(WI01, gb);
      float a1 = dot4(WI10, ga) + dot4(WI11, gb);
      float a2 = dot4(WI20, ga) + dot4(WI21, gb);
      float a3 = dot4(WI30, ga) + dot4(WI31, gb);
      float a4_ = dot4(WI40, ga) + dot4(WI41, gb);
      float a5 = dot4(WI50, ga) + dot4(WI51, gb);
      a0 = wred(a0); a1 = wred(a1); a2 = wred(a2);
      a3 = wred(a3); a4_ = wred(a4_); a5 = wred(a5);
      if (lane == 0) {
        float ir0 = a0 + BI0, iz0 = a1 + BI1, in0 = a2 + BI2;
        float rg0 = 1.f / (1.f + expf(-(ir0 + ghr0)));
        float zg0 = 1.f / (1.f + expf(-(iz0 + ghz0)));
        float ng0 = tanhf(in0 + rg0 * ghn0);
        float hp0 = ld1c(ws + OFF_HS + s * HDIM + r0);
        gstore(ws + OFF_HS + (s + 1) * HDIM + r0, (1.f - zg0) * ng0 + zg0 * hp0);
        float ir1 = a3 + BI3, iz1 = a4_ + BI4, in1 = a5 + BI5;
        float rg1 = 1.f / (1.f + expf(-(ir1 + ghr1)));
        float zg1 = 1.f / (1.f + expf(-(iz1 + ghz1)));
        float ng1 = tanhf(in1 + rg1 * ghn1);
        float hp1 = ld1c(ws + OFF_HS + s * HDIM + r1);
        gstore(ws + OFF_HS + (s + 1) * HDIM + r1, (1.f - zg1) * ng1 + zg1 * hp1);
      }
    }
    gbar(ws, bar++);
  }
}

// logits: LDS-tiled GEMM. 256 rows/block, k-chunks of 32, thread-owns-row.
// Swizzled wl layout WL(row,q)=q*1032+4*row: reads contiguous 1KB/wave
// (conflict-free); writes <=2-way (free).
#define WL(row, q) ((q) * 1032 + 4 * (row))
__global__ void __launch_bounds__(256) k_final2(const float* __restrict__ ow,
                                                const float* __restrict__ ob,
                                                const float* __restrict__ ws,
                                                float* __restrict__ out) {
  __shared__ __align__(16) float wl[8 * 1032];
  __shared__ __align__(16) float hl[T_STEPS * 512];
  int tid = threadIdx.x;
  long rbase = (long)blockIdx.x * 256;
  for (int i = tid; i < T_STEPS * 512; i += 256) hl[i] = ws[OFF_HS + 512 + i];
  float4 st[8];
#pragma unroll
  for (int i = 0; i < 8; ++i) {
    int f = tid + 256 * i; int row = f >> 3, q = f & 7;
    long r = rbase + row;
    st[i] = (r < V) ? *(const float4*)(ow + r * 512 + 4 * q) : make_float4(0.f, 0.f, 0.f, 0.f);
  }
  float acc[T_STEPS];
#pragma unroll
  for (int s = 0; s < T_STEPS; ++s) acc[s] = 0.f;
  __syncthreads();
  for (int c = 0; c < 16; ++c) {
#pragma unroll
    for (int i = 0; i < 8; ++i) {
      int f = tid + 256 * i; int row = f >> 3, q = f & 7;
      *(float4*)(&wl[WL(row, q)]) = st[i];
    }
    __syncthreads();
    if (c < 15) {
#pragma unroll
      for (int i = 0; i < 8; ++i) {
        int f = tid + 256 * i; int row = f >> 3, q = f & 7;
        long r = rbase + row;
        st[i] = (r < V) ? *(const float4*)(ow + r * 512 + (c + 1) * 32 + 4 * q) : make_float4(0.f, 0.f, 0.f, 0.f);
      }
    }
#pragma unroll
    for (int kq = 0; kq < 8; ++kq) {
      float4 w4 = *(const float4*)(&wl[WL(tid, kq)]);
      const float* hb = hl + c * 32 + 4 * kq;
#pragma unroll
      for (int s = 0; s < T_STEPS; ++s) {
        float4 h4 = *(const float4*)(hb + s * 512);
        acc[s] += dot4(w4, h4);
      }
    }
    __syncthreads();
  }
  long r = rbase + tid;
  if (r < V) {
    float b = ob[r];
#pragma unroll
    for (int s = 0; s < T_STEPS; ++s) out[OUT_LOGITS + (long)s * V + r] = acc[s] + b;
  }
}

extern "C" void kernel_launch(void* const* d_in, const int* in_sizes, int n_in,
                              void* d_out, int out_size, void* d_ws, size_t ws_size,
                              hipStream_t stream) {
  const int*   input_tok  = (const int*)d_in[0];
  const float* hidden     = (const float*)d_in[1];
  const float* enc        = (const float*)d_in[2];
  const float* prop       = (const float*)d_in[3];
  const int*   obj_mask   = (const int*)d_in[4];
  const int*   lang_mask  = (const int*)d_in[5];
  const int*   ans        = (const int*)d_in[6];
  const float* emb        = (const float*)d_in[7];
  const float* attn_w1    = (const float*)d_in[8];
  const float* attn_b1    = (const float*)d_in[9];
  const float* attn_w2    = (const float*)d_in[10];
  const float* attn_b2    = (const float*)d_in[11];
  const float* attn_op_w1 = (const float*)d_in[12];
  const float* attn_op_b1 = (const float*)d_in[13];
  const float* attn_op_w2 = (const float*)d_in[14];
  const float* attn_op_b2 = (const float*)d_in[15];
  const float* cmb_w1     = (const float*)d_in[16];
  const float* cmb_b1     = (const float*)d_in[17];
  const float* cmb_w2     = (const float*)d_in[18];
  const float* cmb_b2     = (const float*)d_in[19];
  const float* gw_ih      = (const float*)d_in[20];
  const float* gw_hh      = (const float*)d_in[21];
  const float* gb_ih      = (const float*)d_in[22];
  const float* gb_hh      = (const float*)d_in[23];
  const float* out_w      = (const float*)d_in[24];
  const float* out_b      = (const float*)d_in[25];
  float* out = (float*)d_out;
  float* ws  = (float*)d_ws;

  // reset the 64 barrier flags (monotonic; first barrier index is 1)
  hipMemsetAsync((char*)d_ws + (size_t)OFF_BAR * 4, 0, 4608, stream);
  k_pre1<<<25, 256, 0, stream>>>(input_tok, ans, emb, hidden, ws);
  k_pre2<<<4864, 256, 0, stream>>>(attn_op_w1, attn_op_b1, attn_w1, attn_b1, cmb_w1, cmb_b1, ws);
  k_mprep<<<512, 256, 0, stream>>>(cmb_w1, prop, enc, ws);
  k_recur<<<NBLK, 256, 0, stream>>>(attn_op_w1, attn_w1, gw_hh, gb_hh,
                                    attn_op_w2, attn_op_b2, attn_w2, attn_b2,
                                    obj_mask, lang_mask, cmb_w2, cmb_b2,
                                    gw_ih, gb_ih, ws, out);
  k_final2<<<(V + 255) / 256, 256, 0, stream>>>(out_w, out_b, ws, out);
}